// Round 2
// baseline (10.794 us; speedup 1.0000x reference)
//
#include <hip/hip_runtime.h>

// Problem constants: B=256, T=256, V=1000, AD=64.
#define BB 256
#define TT 256
#define ADIM 64

// out[b,t,a] = start[b,a] + (t/255) * patterns[id[b],t,a]; everything else in
// the reference is dead code. Data may arrive as fp32 or bf16 (harness decides);
// probe at runtime (both rounds so far: bf16, absmax == 1 bf16 ulp).

typedef unsigned int  u32x4 __attribute__((ext_vector_type(4)));
typedef float         f32x4 __attribute__((ext_vector_type(4)));

static __device__ __forceinline__ float bf_lo(unsigned int u) {
    return __uint_as_float(u << 16);
}
static __device__ __forceinline__ float bf_hi(unsigned int u) {
    return __uint_as_float(u & 0xffff0000u);
}
static __device__ __forceinline__ unsigned short f32_to_bf16_rne(float f) {
    unsigned int x = __float_as_uint(f);
    unsigned int r = x + 0x7fffu + ((x >> 16) & 1u);  // round-to-nearest-even
    return (unsigned short)(r >> 16);
}
static __device__ __forceinline__ unsigned int pack_bf16(float lo, float hi) {
    return (unsigned int)f32_to_bf16_rne(lo) |
           ((unsigned int)f32_to_bf16_rne(hi) << 16);
}

// 512 blocks x 256 threads; each thread handles 4 chunks of 8 'a'-elements
// (same b, same a0; t, t+32, t+64, t+96) -> start loaded once, 4 independent
// pattern loads + 4 independent stores per lane (MLP depth 4, half the waves
// of the previous version).
//
// Key scheduling trick: the bf16-layout loads are issued UNCONDITIONALLY,
// before the dtype ballot resolves. bf16 element offsets are always in-bounds
// regardless of actual dtype (fp32 buffer is 2x the bytes), so this is safe;
// it takes the dtype probe off the load critical path.
__global__ __launch_bounds__(256) void traj_kernel(
    const void* __restrict__ start,     // (B, 64)   fp32 or bf16
    const int*  __restrict__ ids,       // (B,)
    const void* __restrict__ patterns,  // (V, T, 64) fp32 or bf16
    void*       __restrict__ out)       // (B, T, 64) same dtype
{
    const int tid  = threadIdx.x;
    const int beta = blockIdx.x;              // 0..511
    const int b    = beta >> 1;               // block-uniform batch index
    const int t0   = (beta & 1) << 7;         // 0 or 128
    const int tl   = tid >> 3;                // 0..31
    const int a0   = (tid & 7) << 3;          // 0,8,...,56

    const int id = ids[b];                    // uniform -> s_load (issue first)

    const unsigned soff  = ((unsigned)b << 6) + (unsigned)a0;
    const unsigned loff  = ((unsigned)tl << 6) + (unsigned)a0;
    const unsigned pbase = (unsigned)id * (TT * ADIM) + ((unsigned)t0 << 6) + loff;
    const unsigned obase = (((unsigned)b * TT + (unsigned)t0) << 6) + loff;
    const unsigned step  = 32 * ADIM;         // t -> t+32, in elements

    // ---- speculative bf16-layout loads (always issued, always in-bounds)
    const unsigned short* s16 = (const unsigned short*)start + soff;
    const unsigned short* p16 = (const unsigned short*)patterns + pbase;
    u32x4 sv  = *reinterpret_cast<const u32x4*>(s16);
    u32x4 pv0 = *reinterpret_cast<const u32x4*>(p16);
    u32x4 pv1 = *reinterpret_cast<const u32x4*>(p16 + step);
    u32x4 pv2 = *reinterpret_cast<const u32x4*>(p16 + 2 * step);
    u32x4 pv3 = *reinterpret_cast<const u32x4*>(p16 + 3 * step);

    // ---- barrier-free dtype probe, in parallel with the gather above.
    // Every wave samples the SAME first 512 bytes of start (256 bf16-interp
    // halves). fp32 data -> ~128 random-exponent low-halves -> some |v|>1e4
    // with overwhelming probability. Identical data -> wave-uniform ballot.
    bool isbf;
    {
        const unsigned long long* q = (const unsigned long long*)start;
        unsigned long long d = q[tid & 63];
        bool big = false;
#pragma unroll
        for (int i = 0; i < 4; ++i) {
            float v = __uint_as_float(((unsigned int)(unsigned short)(d >> (16 * i))) << 16);
            big |= !(fabsf(v) <= 1.0e4f);   // catches big values and NaN
        }
        isbf = (__ballot(big) == 0ull);
    }

    const int   t1 = t0 + tl;
    const float w0 = (float)t1        * (1.0f / 255.0f);  // linspace(0,1,256)[t]
    const float w1 = (float)(t1 + 32) * (1.0f / 255.0f);
    const float w2 = (float)(t1 + 64) * (1.0f / 255.0f);
    const float w3 = (float)(t1 + 96) * (1.0f / 255.0f);

    if (isbf) {
        unsigned short* o16 = (unsigned short*)out + obase;
        u32x4 o0, o1, o2, o3;
#pragma unroll
        for (int i = 0; i < 4; ++i) {
            const float slo = bf_lo(sv[i]);
            const float shi = bf_hi(sv[i]);
            o0[i] = pack_bf16(fmaf(w0, bf_lo(pv0[i]), slo), fmaf(w0, bf_hi(pv0[i]), shi));
            o1[i] = pack_bf16(fmaf(w1, bf_lo(pv1[i]), slo), fmaf(w1, bf_hi(pv1[i]), shi));
            o2[i] = pack_bf16(fmaf(w2, bf_lo(pv2[i]), slo), fmaf(w2, bf_hi(pv2[i]), shi));
            o3[i] = pack_bf16(fmaf(w3, bf_lo(pv3[i]), slo), fmaf(w3, bf_hi(pv3[i]), shi));
        }
        __builtin_nontemporal_store(o0, reinterpret_cast<u32x4*>(o16));
        __builtin_nontemporal_store(o1, reinterpret_cast<u32x4*>(o16 + step));
        __builtin_nontemporal_store(o2, reinterpret_cast<u32x4*>(o16 + 2 * step));
        __builtin_nontemporal_store(o3, reinterpret_cast<u32x4*>(o16 + 3 * step));
    } else {
        const float* sf = (const float*)start + soff;
        const float* pf = (const float*)patterns + pbase;
        float*       of = (float*)out + obase;

        f32x4 s0 = ((const f32x4*)sf)[0];
        f32x4 s1 = ((const f32x4*)sf)[1];
#pragma unroll
        for (int k = 0; k < 4; ++k) {
            const float w = (float)(t1 + 32 * k) * (1.0f / 255.0f);
            f32x4 pa = ((const f32x4*)(pf + k * step))[0];
            f32x4 pb = ((const f32x4*)(pf + k * step))[1];
            f32x4 ra, rb;
#pragma unroll
            for (int i = 0; i < 4; ++i) {
                ra[i] = fmaf(w, pa[i], s0[i]);
                rb[i] = fmaf(w, pb[i], s1[i]);
            }
            __builtin_nontemporal_store(ra, (f32x4*)(of + k * step));
            __builtin_nontemporal_store(rb, (f32x4*)(of + k * step) + 1);
        }
    }
}

extern "C" void kernel_launch(void* const* d_in, const int* in_sizes, int n_in,
                              void* d_out, int out_size, void* d_ws, size_t ws_size,
                              hipStream_t stream) {
    // setup_inputs() dict order: 0=start_state, 1=instruction_id, ..., 27=patterns
    const void* start = d_in[0];
    const int*  ids   = (const int*)d_in[1];
    int pat_idx = n_in - 1;
    // defensive: patterns is the unique input with V*T*AD = 16,384,000 elems
    for (int i = 0; i < n_in; ++i) {
        if (in_sizes[i] == 1000 * 256 * 64) { pat_idx = i; break; }
    }
    const void* patterns = d_in[pat_idx];

    // B*T*64 elems / (4 chunks x 8 elems per thread) / 256 threads = 512 blocks
    traj_kernel<<<512, 256, 0, stream>>>(start, ids, patterns, d_out);
}

// Round 3
// 10.289 us; speedup vs baseline: 1.0490x; 1.0490x over previous
//
#include <hip/hip_runtime.h>

// Problem constants: B=256, T=256, V=1000, AD=64.
#define BB 256
#define TT 256
#define ADIM 64

// out[b,t,a] = start[b,a] + (t/255) * patterns[id[b],t,a]; everything else in
// the reference is dead code. Data may arrive as fp32 or bf16 (harness decides);
// probe at runtime (all rounds so far: bf16, absmax == 1 bf16 ulp).

typedef unsigned int  u32x4 __attribute__((ext_vector_type(4)));
typedef float         f32x4 __attribute__((ext_vector_type(4)));

static __device__ __forceinline__ float bf_lo(unsigned int u) {
    return __uint_as_float(u << 16);
}
static __device__ __forceinline__ float bf_hi(unsigned int u) {
    return __uint_as_float(u & 0xffff0000u);
}
static __device__ __forceinline__ unsigned short f32_to_bf16_rne(float f) {
    unsigned int x = __float_as_uint(f);
    unsigned int r = x + 0x7fffu + ((x >> 16) & 1u);  // round-to-nearest-even
    return (unsigned short)(r >> 16);
}
static __device__ __forceinline__ unsigned int pack_bf16(float lo, float hi) {
    return (unsigned int)f32_to_bf16_rne(lo) |
           ((unsigned int)f32_to_bf16_rne(hi) << 16);
}

// 256 blocks x 1024 threads (one block per batch row b): each thread handles
// 2 chunks of 8 'a'-elements (t and t+128). Same 4096-wave / MLP-2 shape as
// the best round (9.91 us), but 4x fewer workgroups (shorter dispatch ramp),
// one scalar ids[] load per block, and speculative loads issued before the
// dtype ballot resolves (bf16 offsets are in-bounds for either dtype since
// the fp32 buffer is 2x the bytes).
__global__ __launch_bounds__(1024) void traj_kernel(
    const void* __restrict__ start,     // (B, 64)   fp32 or bf16
    const int*  __restrict__ ids,       // (B,)
    const void* __restrict__ patterns,  // (V, T, 64) fp32 or bf16
    void*       __restrict__ out)       // (B, T, 64) same dtype
{
    const int tid = threadIdx.x;              // 0..1023
    const int b   = blockIdx.x;               // 0..255, block-uniform
    const int tl  = tid >> 3;                 // 0..127  (t and t+128)
    const int a0  = (tid & 7) << 3;           // 0,8,...,56

    const int id = ids[b];                    // uniform -> one s_load per block

    const unsigned soff  = ((unsigned)b << 6) + (unsigned)a0;
    const unsigned loff  = ((unsigned)tl << 6) + (unsigned)a0;
    const unsigned pbase = (unsigned)id * (TT * ADIM) + loff;
    const unsigned obase = (((unsigned)b * TT) << 6) + loff;
    const unsigned step  = 128 * ADIM;        // t -> t+128, in elements

    // ---- speculative bf16-layout loads (always issued, always in-bounds)
    const unsigned short* s16 = (const unsigned short*)start + soff;
    const unsigned short* p16 = (const unsigned short*)patterns + pbase;
    u32x4 sv  = *reinterpret_cast<const u32x4*>(s16);
    u32x4 pv0 = *reinterpret_cast<const u32x4*>(p16);
    u32x4 pv1 = *reinterpret_cast<const u32x4*>(p16 + step);

    // ---- barrier-free dtype probe, overlapped with the gather above.
    // Every wave samples the SAME first 512 bytes of start (256 bf16-interp
    // halves). fp32 data -> ~128 random-exponent low-halves -> some |v|>1e4
    // with overwhelming probability. Identical data -> wave-uniform ballot.
    bool isbf;
    {
        const unsigned long long* q = (const unsigned long long*)start;
        unsigned long long d = q[tid & 63];
        bool big = false;
#pragma unroll
        for (int i = 0; i < 4; ++i) {
            float v = __uint_as_float(((unsigned int)(unsigned short)(d >> (16 * i))) << 16);
            big |= !(fabsf(v) <= 1.0e4f);   // catches big values and NaN
        }
        isbf = (__ballot(big) == 0ull);
    }

    const float w0 = (float)tl         * (1.0f / 255.0f);  // linspace(0,1,256)[t]
    const float w1 = (float)(tl + 128) * (1.0f / 255.0f);

    if (isbf) {
        unsigned short* o16 = (unsigned short*)out + obase;
        u32x4 o0, o1;
#pragma unroll
        for (int i = 0; i < 4; ++i) {
            const float slo = bf_lo(sv[i]);
            const float shi = bf_hi(sv[i]);
            o0[i] = pack_bf16(fmaf(w0, bf_lo(pv0[i]), slo), fmaf(w0, bf_hi(pv0[i]), shi));
            o1[i] = pack_bf16(fmaf(w1, bf_lo(pv1[i]), slo), fmaf(w1, bf_hi(pv1[i]), shi));
        }
        __builtin_nontemporal_store(o0, reinterpret_cast<u32x4*>(o16));
        __builtin_nontemporal_store(o1, reinterpret_cast<u32x4*>(o16 + step));
    } else {
        const float* sf = (const float*)start + soff;
        const float* pf = (const float*)patterns + pbase;
        float*       of = (float*)out + obase;

        f32x4 s0 = ((const f32x4*)sf)[0];
        f32x4 s1 = ((const f32x4*)sf)[1];
        f32x4 a0v = ((const f32x4*)pf)[0];
        f32x4 a1v = ((const f32x4*)pf)[1];
        f32x4 b0v = ((const f32x4*)(pf + step))[0];
        f32x4 b1v = ((const f32x4*)(pf + step))[1];

        f32x4 r10, r11, r20, r21;
#pragma unroll
        for (int i = 0; i < 4; ++i) {
            r10[i] = fmaf(w0, a0v[i], s0[i]);
            r11[i] = fmaf(w0, a1v[i], s1[i]);
            r20[i] = fmaf(w1, b0v[i], s0[i]);
            r21[i] = fmaf(w1, b1v[i], s1[i]);
        }
        __builtin_nontemporal_store(r10, (f32x4*)of);
        __builtin_nontemporal_store(r11, (f32x4*)of + 1);
        __builtin_nontemporal_store(r20, (f32x4*)(of + step));
        __builtin_nontemporal_store(r21, (f32x4*)(of + step) + 1);
    }
}

extern "C" void kernel_launch(void* const* d_in, const int* in_sizes, int n_in,
                              void* d_out, int out_size, void* d_ws, size_t ws_size,
                              hipStream_t stream) {
    // setup_inputs() dict order: 0=start_state, 1=instruction_id, ..., 27=patterns
    const void* start = d_in[0];
    const int*  ids   = (const int*)d_in[1];
    int pat_idx = n_in - 1;
    // defensive: patterns is the unique input with V*T*AD = 16,384,000 elems
    for (int i = 0; i < n_in; ++i) {
        if (in_sizes[i] == 1000 * 256 * 64) { pat_idx = i; break; }
    }
    const void* patterns = d_in[pat_idx];

    // One block per b: 256 blocks x 1024 threads, 2 chunks x 8 elems/thread
    traj_kernel<<<256, 1024, 0, stream>>>(start, ids, patterns, d_out);
}